// Round 11
// baseline (198.484 us; speedup 1.0000x reference)
//
#include <hip/hip_runtime.h>

#define F_IN   128
#define F_OUT  128
// bucket width = 512 nodes (power of 2: bucket = src>>9, local = src&511).
// Requires N <= 131072 (17-bit dst, <=256 buckets) — guarded at launch.

typedef __attribute__((ext_vector_type(8))) short short8;
typedef __attribute__((ext_vector_type(4))) float floatx4;

__device__ __forceinline__ float bf16u_to_f_lo(unsigned int u) {
    union { unsigned int i; float f; } c; c.i = u << 16; return c.f;
}
__device__ __forceinline__ float bf16u_to_f_hi(unsigned int u) {
    union { unsigned int i; float f; } c; c.i = u & 0xffff0000u; return c.f;
}
__device__ __forceinline__ unsigned short f_to_bf16(float f) {
    union { float f; unsigned int i; } c; c.f = f;
    unsigned int u = c.i;
    u += 0x7fffu + ((u >> 16) & 1u);   // round-to-nearest-even
    return (unsigned short)(u >> 16);
}
__device__ __forceinline__ unsigned int pack2(unsigned short a, unsigned short b) {
    return (unsigned int)a | ((unsigned int)b << 16);
}

// async 16B global -> LDS (wave-uniform LDS base + lane*16)
__device__ __forceinline__ void gload_lds16(const void* g, void* l) {
    __builtin_amdgcn_global_load_lds(
        (const __attribute__((address_space(1))) unsigned int*)g,
        (__attribute__((address_space(3))) unsigned int*)l, 16, 0, 0);
}

// ---------------------------------------------------------------------------
// D1: fused init (R7-proven). Grid = nbconv + nbhist + 1 blocks.
//  - blocks [0, nbconv): convert x row-seg -> bf16 mirror in out bytes
//    [256,512) of each 512B row
//  - blocks [nbconv, nbconv+nbhist): coarse 256-bucket edge histogram
//    (LDS pre-aggregated -> global atomics into btot, zeroed by memset)
//  - last block: stage [W|B] bf16 MFMA fragments into bfrag
// ---------------------------------------------------------------------------
__global__ __launch_bounds__(256) void init_kernel(const float* __restrict__ x,
                                                   char* __restrict__ outb,
                                                   const float* __restrict__ W,
                                                   const float* __restrict__ Bm,
                                                   uint4* __restrict__ bfrag,
                                                   int* __restrict__ btot,
                                                   const int* __restrict__ ei,
                                                   int N, int E, int nbconv, int nbhist) {
    int b = blockIdx.x;
    int t = threadIdx.x;
    if (b < nbconv) {
        long tid = (long)b * 256 + t;
        if (tid < (long)N * 32) {
            int row = (int)(tid >> 5);
            int seg = (int)(tid & 31);
            float4 v = *(const float4*)(x + (size_t)row * 128 + seg * 4);
            unsigned short r[4] = {f_to_bf16(v.x), f_to_bf16(v.y), f_to_bf16(v.z), f_to_bf16(v.w)};
            *(ushort4*)(outb + (size_t)row * 512 + 256 + seg * 8) =
                make_ushort4(r[0], r[1], r[2], r[3]);
        }
        return;
    }
    if (b < nbconv + nbhist) {
        __shared__ int h[256];
        h[t] = 0;
        __syncthreads();
        int e0 = (b - nbconv) * 1024;
#pragma unroll
        for (int j = 0; j < 4; ++j) {
            int idx = e0 + j * 256 + t;
            if (idx < E) atomicAdd(&h[ei[idx] >> 9], 1);
        }
        __syncthreads();
        if (h[t]) atomicAdd(&btot[t], h[t]);
        return;
    }
    // ---- last block: stage bfrag ----
#pragma unroll
    for (int i = 0; i < 16; ++i) {
        int flat = i * 256 + t;          // 0..4095 = (nt*8+s)*64 + lane
        int lane = flat & 63;
        int idx = flat >> 6;
        int nt = idx >> 3, sfrag = idx & 7;
        int n = nt * 16 + (lane & 15);
        int kbase = sfrag * 32 + (lane >> 4) * 8;
        const float* srcp = (kbase < 128) ? (W + n * 128 + kbase)
                                          : (Bm + n * 128 + (kbase - 128));
        float4 v0 = *(const float4*)srcp;
        float4 v1 = *(const float4*)(srcp + 4);
        uint4 pk;
        pk.x = pack2(f_to_bf16(v0.x), f_to_bf16(v0.y));
        pk.y = pack2(f_to_bf16(v0.z), f_to_bf16(v0.w));
        pk.z = pack2(f_to_bf16(v1.x), f_to_bf16(v1.y));
        pk.w = pack2(f_to_bf16(v1.z), f_to_bf16(v1.w));
        bfrag[flat] = pk;
    }
}

// ---------------------------------------------------------------------------
// D2: exclusive scan of bucket totals (1 block). gbase[NB] = grand total.
// gcur starts as a mutable copy for pass1's per-block run allocation.
// ---------------------------------------------------------------------------
__global__ __launch_bounds__(256) void scan256_kernel(const int* __restrict__ btot,
                                                      int* __restrict__ gbase,
                                                      int* __restrict__ gcur, int NB) {
    __shared__ int s[256];
    int t = threadIdx.x;
    s[t] = (t < NB) ? btot[t] : 0;
    __syncthreads();
    for (int d = 1; d < 256; d <<= 1) {
        int v = s[t] + ((t >= d) ? s[t - d] : 0);
        __syncthreads();
        s[t] = v;
        __syncthreads();
    }
    int excl = (t > 0) ? s[t - 1] : 0;
    if (t < NB) { gbase[t] = excl; gcur[t] = excl; }
    if (t == 0) gbase[NB] = s[255];
}

// ---------------------------------------------------------------------------
// D3: bucket scatter. Each block: 1024 contiguous edges (coalesced reads),
// LDS per-bucket count -> ONE global atomicAdd per bucket (run allocation),
// then per-edge LDS rank -> write packed (local<<17 | dst) into the bucket
// region. Same-block writes fill whole lines -> ~no write amplification.
// ---------------------------------------------------------------------------
__global__ __launch_bounds__(256) void pass1_kernel(const int* __restrict__ ei,
                                                    int* __restrict__ gcur,
                                                    int* __restrict__ ebuf, int E) {
    __shared__ int cnt[256];
    __shared__ int base[256];
    __shared__ int cur[256];
    int t = threadIdx.x;
    cnt[t] = 0;
    cur[t] = 0;
    int e0 = blockIdx.x * 1024;
    __syncthreads();
    int s[4];
#pragma unroll
    for (int j = 0; j < 4; ++j) {
        int idx = e0 + j * 256 + t;
        s[j] = (idx < E) ? ei[idx] : -1;
        if (s[j] >= 0) atomicAdd(&cnt[s[j] >> 9], 1);
    }
    __syncthreads();
    int c = cnt[t];
    base[t] = c ? atomicAdd(&gcur[t], c) : 0;
    __syncthreads();
#pragma unroll
    for (int j = 0; j < 4; ++j) {
        if (s[j] >= 0) {
            int idx = e0 + j * 256 + t;
            int bkt = s[j] >> 9;
            int r = atomicAdd(&cur[bkt], 1);
            int d = ei[E + idx];
            ebuf[base[bkt] + r] = ((s[j] & 511) << 17) | d;
        }
    }
}

// ---------------------------------------------------------------------------
// D4: per-bucket CSR finalize. Block g streams its contiguous ebuf region
// twice (L2-hot, coalesced): count per local node -> LDS scan(512) -> write
// off[] segment ENDS + place dsts contiguously into dst_sorted.
// ---------------------------------------------------------------------------
__global__ __launch_bounds__(256) void pass2_kernel(const int* __restrict__ ebuf,
                                                    const int* __restrict__ gbase,
                                                    int* __restrict__ off,
                                                    int* __restrict__ dst_sorted,
                                                    int N, int NB) {
    __shared__ int sc[512];
    __shared__ int cur[512];
    int g = blockIdx.x, t = threadIdx.x;
    int lo = g << 9;
    int hi = min(N, lo + 512);
    int start = gbase[g];
    int end = gbase[g + 1];
    sc[t] = 0;
    sc[t + 256] = 0;
    __syncthreads();
    for (int i = start + t; i < end; i += 256) atomicAdd(&sc[ebuf[i] >> 17], 1);
    __syncthreads();
    for (int d = 1; d < 512; d <<= 1) {
        int v0 = sc[t] + ((t >= d) ? sc[t - d] : 0);
        int i1 = t + 256;
        int v1 = sc[i1] + sc[i1 - d];
        __syncthreads();
        sc[t] = v0;
        sc[i1] = v1;
        __syncthreads();
    }
    if (lo + t < hi) off[lo + t] = start + sc[t];              // segment END
    cur[t] = (t == 0) ? 0 : sc[t - 1];
    {
        int i1 = t + 256;
        if (lo + i1 < hi) off[lo + i1] = start + sc[i1];
        cur[i1] = sc[i1 - 1];
    }
    __syncthreads();
    for (int i = start + t; i < end; i += 256) {
        int v = ebuf[i];
        int n = v >> 17;
        int r = atomicAdd(&cur[n], 1);
        dst_sorted[start + r] = v & 0x1FFFF;
    }
}

// ---------------------------------------------------------------------------
// D5: gather-aggregate (bf16 in/out, fp32 accumulate). 16 lanes/node,
// single predicated 8-wide batch per latency-round. Reads mirror half of out
// rows, writes agg bf16 into bytes [0,256) of the node's own out row
// (16 lanes x 16B = 256B aligned contiguous -> full lines, no RMW).
// ---------------------------------------------------------------------------
__global__ __launch_bounds__(256) void gather_bf16_kernel(const int* __restrict__ off,
                                                          const int* __restrict__ dst_sorted,
                                                          char* __restrict__ outb, int N) {
    int node = blockIdx.x * 16 + (threadIdx.x >> 4);
    int lane = threadIdx.x & 15;
    if (node >= N) return;
    int start = (node == 0) ? 0 : off[node - 1];
    int end = off[node];
    float acc[8];
#pragma unroll
    for (int i = 0; i < 8; ++i) acc[i] = 0.0f;

    const char* xb = outb;
    for (int j = start; j < end; j += 8) {
        uint4 v[8];
#pragma unroll
        for (int i = 0; i < 8; ++i) {
            int idx = j + i;
            int clamped = (idx < end) ? idx : (end - 1);
            int d = dst_sorted[clamped];
            v[i] = *(const uint4*)(xb + (size_t)d * 512 + 256 + lane * 16);
        }
#pragma unroll
        for (int i = 0; i < 8; ++i) {
            if (j + i >= end) v[i] = make_uint4(0u, 0u, 0u, 0u);  // mask (bf16 0 == +0.0f)
            acc[0] += bf16u_to_f_lo(v[i].x); acc[1] += bf16u_to_f_hi(v[i].x);
            acc[2] += bf16u_to_f_lo(v[i].y); acc[3] += bf16u_to_f_hi(v[i].y);
            acc[4] += bf16u_to_f_lo(v[i].z); acc[5] += bf16u_to_f_hi(v[i].z);
            acc[6] += bf16u_to_f_lo(v[i].w); acc[7] += bf16u_to_f_hi(v[i].w);
        }
    }
    int deg = end - start;
    float scale = (deg > 0) ? (1.0f / (float)deg) : 1.0f;
    unsigned short r[8];
#pragma unroll
    for (int i = 0; i < 8; ++i) r[i] = f_to_bf16(acc[i] * scale);
    uint4 pk;
    pk.x = pack2(r[0], r[1]);
    pk.y = pack2(r[2], r[3]);
    pk.z = pack2(r[4], r[5]);
    pk.w = pack2(r[6], r[7]);
    *(uint4*)(outb + (size_t)node * 512 + lane * 16) = pk;
}

// ---------------------------------------------------------------------------
// D6: MFMA GEMM. One 128-row tile per block; A = bf16 [agg|mirror] in out
// rows (K=256), M = [W;B] frags pre-staged in bfrag, async-copied 64KB to
// LDS; all 16 A-frag loads issued upfront (max MLP). NEW EPILOGUE: after the
// MFMAs, Bs is reused as per-wave fp32 staging (each wave's private 16KB) and
// the output leaves as float4 stores covering whole 512B rows — full-line
// writes, no write-allocate RMW (R4 counters: WRITE 94MB vs 51 ideal with the
// old scattered-dword epilogue). One barrier after the last Bs read; each
// wave reads only its own staging region, so no second barrier needed.
// In-place: each wave reads only its own rows before storing them.
// ---------------------------------------------------------------------------
__global__ __launch_bounds__(256, 2) void gemm_mfma_kernel(const uint4* __restrict__ bfrag,
                                                           float* __restrict__ out, int N) {
    __shared__ uint4 Bs[4096];  // 64 KB: B-frags, then per-wave fp32 C staging
    int t = threadIdx.x;
    int lane = t & 63;
    int w = t >> 6;
    int m16 = lane & 15;
    int quad = lane >> 4;

#pragma unroll
    for (int j = 0; j < 16; ++j)
        gload_lds16(bfrag + (w * 16 + j) * 64 + lane, &Bs[(w * 16 + j) * 64]);

    int rowbase = blockIdx.x * 128 + w * 32;
    short8 afrag[2][8];
#pragma unroll
    for (int g = 0; g < 2; ++g) {
        int arow = rowbase + g * 16 + m16;
        if (arow > N - 1) arow = N - 1;  // clamp; pollutes only discarded rows
        const char* ab = (const char*)out + (size_t)arow * 512;
#pragma unroll
        for (int s = 0; s < 8; ++s)
            afrag[g][s] = *(const short8*)(ab + s * 64 + quad * 16);
    }
    __syncthreads();   // drains global_load_lds (vmcnt) + barrier

    floatx4 acc[2][8];
#pragma unroll
    for (int g = 0; g < 2; ++g)
#pragma unroll
        for (int nt = 0; nt < 8; ++nt) acc[g][nt] = (floatx4){0.f, 0.f, 0.f, 0.f};

#pragma unroll
    for (int nt = 0; nt < 8; ++nt) {
#pragma unroll
        for (int s = 0; s < 8; ++s) {
            short8 bf = *(const short8*)&Bs[(nt * 8 + s) * 64 + lane];
            acc[0][nt] = __builtin_amdgcn_mfma_f32_16x16x32_bf16(afrag[0][s], bf, acc[0][nt], 0, 0, 0);
            acc[1][nt] = __builtin_amdgcn_mfma_f32_16x16x32_bf16(afrag[1][s], bf, acc[1][nt], 0, 0, 0);
        }
    }
    __syncthreads();   // all waves done reading B-frags; Bs becomes C staging

    // ---- stage C in per-wave LDS region: [32 rows][128 cols] fp32 ----
    float* fs = (float*)Bs + w * 4096;   // 16 KB per wave
#pragma unroll
    for (int g = 0; g < 2; ++g)
#pragma unroll
        for (int nt = 0; nt < 8; ++nt)
#pragma unroll
            for (int r = 0; r < 4; ++r)
                fs[(g * 16 + quad * 4 + r) * 128 + nt * 16 + m16] = acc[g][nt][r];
    // no barrier: each wave reads only its own region (wave-coherent LDS)
    __builtin_amdgcn_s_waitcnt(0);       // lgkmcnt(0): own ds_writes complete

    // ---- write out as full 512B rows: 2 rows/pass x 32 lanes x float4 ----
#pragma unroll
    for (int p = 0; p < 16; ++p) {
        int lrow = p * 2 + (lane >> 5);
        float4 v = *(const float4*)&fs[lrow * 128 + (lane & 31) * 4];
        int gr = rowbase + lrow;
        if (gr < N) *(float4*)&out[(size_t)gr * 128 + (lane & 31) * 4] = v;
    }
}

// ---------------------------------------------------------------------------
// Atomic-scatter fallback (tiny ws / out-of-range N).
// ---------------------------------------------------------------------------
__global__ void zero_kernel(int* __restrict__ p, long n) {
    long i = (long)blockIdx.x * blockDim.x + threadIdx.x;
    long stride = (long)gridDim.x * blockDim.x;
    for (; i < n; i += stride) p[i] = 0;
}

__global__ void invdeg_kernel(int* __restrict__ deg_io, int N) {
    int i = blockIdx.x * blockDim.x + threadIdx.x;
    if (i < N) {
        int d = deg_io[i];
        float inv = (d > 0) ? (1.0f / (float)d) : 1.0f;
        ((float*)deg_io)[i] = inv;
    }
}

__global__ void hist_kernel(const int* __restrict__ src, int* __restrict__ cnt, int E) {
    int e = blockIdx.x * blockDim.x + threadIdx.x;
    if (e < E) atomicAdd(&cnt[src[e]], 1);
}

__global__ __launch_bounds__(128) void scatter_atomic_kernel(const float* __restrict__ x,
                                                             const int* __restrict__ ei,
                                                             const float* __restrict__ invdeg,
                                                             float* __restrict__ out, int E) {
    int e = blockIdx.x;
    int f = threadIdx.x;
    int s = ei[e];
    int d = ei[E + e];
    float v = x[(long)d * F_IN + f] * invdeg[s];
    atomicAdd(&out[(long)s * F_IN + f], v);
}

__global__ __launch_bounds__(256) void gemm_fused_kernel(const float* __restrict__ x,
                                                         const float* __restrict__ W,
                                                         const float* __restrict__ Bm,
                                                         float* __restrict__ out, int N) {
    __shared__ float As[64][68];
    __shared__ float Ms[64][132];
    int t = threadIdx.x;
    int row0 = blockIdx.x * 64;
    int c0 = (t & 31) * 4;
    int r0 = (t >> 5) * 8;
    float acc[8][4];
#pragma unroll
    for (int i = 0; i < 8; ++i)
#pragma unroll
        for (int j = 0; j < 4; ++j) acc[i][j] = 0.0f;

    for (int kc = 0; kc < 4; ++kc) {
        const float* Asrc = (kc < 2) ? out : x;
        const float* Msrc = (kc < 2) ? W : Bm;
        int k0 = (kc & 1) * 64;
#pragma unroll
        for (int i = 0; i < 4; ++i) {
            int flat = t + 256 * i;
            int m = flat >> 4, ks = flat & 15;
            int row = row0 + m;
            float4 v = make_float4(0.f, 0.f, 0.f, 0.f);
            if (row < N) v = *(const float4*)&Asrc[(long)row * 128 + k0 + ks * 4];
            As[ks * 4 + 0][m] = v.x;
            As[ks * 4 + 1][m] = v.y;
            As[ks * 4 + 2][m] = v.z;
            As[ks * 4 + 3][m] = v.w;
        }
#pragma unroll
        for (int i = 0; i < 8; ++i) {
            int flat = t + 256 * i;
            int c = flat >> 4, ks = flat & 15;
            float4 v = *(const float4*)&Msrc[(long)c * 128 + k0 + ks * 4];
            Ms[ks * 4 + 0][c] = v.x;
            Ms[ks * 4 + 1][c] = v.y;
            Ms[ks * 4 + 2][c] = v.z;
            Ms[ks * 4 + 3][c] = v.w;
        }
        __syncthreads();
#pragma unroll 8
        for (int kk = 0; kk < 64; ++kk) {
            float4 a0 = *(const float4*)&As[kk][r0];
            float4 a1 = *(const float4*)&As[kk][r0 + 4];
            float4 m0 = *(const float4*)&Ms[kk][c0];
            float a[8] = {a0.x, a0.y, a0.z, a0.w, a1.x, a1.y, a1.z, a1.w};
            float m[4] = {m0.x, m0.y, m0.z, m0.w};
#pragma unroll
            for (int i = 0; i < 8; ++i)
#pragma unroll
                for (int j = 0; j < 4; ++j) acc[i][j] += a[i] * m[j];
        }
        __syncthreads();
    }
#pragma unroll
    for (int i = 0; i < 8; ++i) {
        int row = row0 + r0 + i;
        if (row < N) {
            float4 v = make_float4(acc[i][0], acc[i][1], acc[i][2], acc[i][3]);
            *(float4*)&out[(long)row * 128 + c0] = v;
        }
    }
}

// ---------------------------------------------------------------------------

extern "C" void kernel_launch(void* const* d_in, const int* in_sizes, int n_in,
                              void* d_out, int out_size, void* d_ws, size_t ws_size,
                              hipStream_t stream) {
    const float* x = (const float*)d_in[0];
    const int* ei = (const int*)d_in[1];     // int32 per harness contract
    const float* W = (const float*)d_in[2];
    const float* Bm = (const float*)d_in[3];
    float* out = (float*)d_out;

    const int N = in_sizes[0] / F_IN;   // 100000
    const int E = in_sizes[1] / 2;      // 625000
    const int NB = (N + 511) >> 9;      // buckets of 512 nodes
    const int nbconv = (int)(((long)N * 32 + 255) / 256);
    const int nbhist = (E + 1023) / 1024;

    // ws: bfrag[4096 u4] | btot[256] | gbase[260] | gcur[256] | off[N] | ebuf[E] | dst[E]
    const size_t need_main = 4096 * sizeof(uint4) +
                             ((size_t)772 + (size_t)N + 2 * (size_t)E) * sizeof(int);
    const size_t need_deg = (size_t)N * sizeof(int);

    if (ws_size >= need_main && N <= 131072) {
        uint4* bfrag = (uint4*)d_ws;            // 64KB, aligned
        int* btot    = (int*)(bfrag + 4096);
        int* gbase   = btot + 256;              // NB+1 entries (<=257)
        int* gcur    = gbase + 260;
        int* off     = gcur + 256;
        int* ebuf    = off + N;
        int* dst_sorted = ebuf + E;

        hipMemsetAsync(btot, 0, 256 * sizeof(int), stream);
        init_kernel<<<nbconv + nbhist + 1, 256, 0, stream>>>(x, (char*)out, W, Bm,
                                                             bfrag, btot, ei, N, E,
                                                             nbconv, nbhist);
        scan256_kernel<<<1, 256, 0, stream>>>(btot, gbase, gcur, NB);
        pass1_kernel<<<(E + 1023) / 1024, 256, 0, stream>>>(ei, gcur, ebuf, E);
        pass2_kernel<<<NB, 256, 0, stream>>>(ebuf, gbase, off, dst_sorted, N, NB);
        gather_bf16_kernel<<<(N + 15) / 16, 256, 0, stream>>>(off, dst_sorted, (char*)out, N);
        gemm_mfma_kernel<<<(N + 127) / 128, 256, 0, stream>>>(bfrag, out, N);
    } else if (ws_size >= need_deg) {
        // -------- atomic scatter fallback --------
        int* deg = (int*)d_ws;
        zero_kernel<<<256, 256, 0, stream>>>(deg, N);
        hist_kernel<<<(E + 255) / 256, 256, 0, stream>>>(ei, deg, E);
        invdeg_kernel<<<(N + 255) / 256, 256, 0, stream>>>(deg, N);
        zero_kernel<<<512, 256, 0, stream>>>((int*)out, (long)N * F_IN);
        scatter_atomic_kernel<<<E, 128, 0, stream>>>(x, ei, (const float*)deg, out, E);
        gemm_fused_kernel<<<(N + 63) / 64, 256, 0, stream>>>(x, W, Bm, out, N);
    }
}

// Round 12
// 192.972 us; speedup vs baseline: 1.0286x; 1.0286x over previous
//
#include <hip/hip_runtime.h>

#define F_IN   128
#define F_OUT  128
// bucket width = 512 nodes (power of 2: bucket = src>>9, local = src&511).
// Requires N <= 131072 (17-bit dst, <=256 buckets) — guarded at launch.

typedef __attribute__((ext_vector_type(8))) short short8;
typedef __attribute__((ext_vector_type(4))) float floatx4;

__device__ __forceinline__ float bf16u_to_f_lo(unsigned int u) {
    union { unsigned int i; float f; } c; c.i = u << 16; return c.f;
}
__device__ __forceinline__ float bf16u_to_f_hi(unsigned int u) {
    union { unsigned int i; float f; } c; c.i = u & 0xffff0000u; return c.f;
}
__device__ __forceinline__ unsigned short f_to_bf16(float f) {
    union { float f; unsigned int i; } c; c.f = f;
    unsigned int u = c.i;
    u += 0x7fffu + ((u >> 16) & 1u);   // round-to-nearest-even
    return (unsigned short)(u >> 16);
}
__device__ __forceinline__ unsigned int pack2(unsigned short a, unsigned short b) {
    return (unsigned int)a | ((unsigned int)b << 16);
}

// async 16B global -> LDS (wave-uniform LDS base + lane*16)
__device__ __forceinline__ void gload_lds16(const void* g, void* l) {
    __builtin_amdgcn_global_load_lds(
        (const __attribute__((address_space(1))) unsigned int*)g,
        (__attribute__((address_space(3))) unsigned int*)l, 16, 0, 0);
}

// ---------------------------------------------------------------------------
// D1: fused init (R7-proven). Grid = nbconv + nbhist + 1 blocks.
//  - blocks [0, nbconv): convert x row-seg -> bf16 mirror in out bytes
//    [256,512) of each 512B row
//  - blocks [nbconv, nbconv+nbhist): coarse 256-bucket edge histogram
//    (LDS pre-aggregated -> global atomics into btot, zeroed by memset)
//  - last block: stage [W|B] bf16 MFMA fragments into bfrag
// ---------------------------------------------------------------------------
__global__ __launch_bounds__(256) void init_kernel(const float* __restrict__ x,
                                                   char* __restrict__ outb,
                                                   const float* __restrict__ W,
                                                   const float* __restrict__ Bm,
                                                   uint4* __restrict__ bfrag,
                                                   int* __restrict__ btot,
                                                   const int* __restrict__ ei,
                                                   int N, int E, int nbconv, int nbhist) {
    int b = blockIdx.x;
    int t = threadIdx.x;
    if (b < nbconv) {
        long tid = (long)b * 256 + t;
        if (tid < (long)N * 32) {
            int row = (int)(tid >> 5);
            int seg = (int)(tid & 31);
            float4 v = *(const float4*)(x + (size_t)row * 128 + seg * 4);
            unsigned short r[4] = {f_to_bf16(v.x), f_to_bf16(v.y), f_to_bf16(v.z), f_to_bf16(v.w)};
            *(ushort4*)(outb + (size_t)row * 512 + 256 + seg * 8) =
                make_ushort4(r[0], r[1], r[2], r[3]);
        }
        return;
    }
    if (b < nbconv + nbhist) {
        __shared__ int h[256];
        h[t] = 0;
        __syncthreads();
        int e0 = (b - nbconv) * 1024;
#pragma unroll
        for (int j = 0; j < 4; ++j) {
            int idx = e0 + j * 256 + t;
            if (idx < E) atomicAdd(&h[ei[idx] >> 9], 1);
        }
        __syncthreads();
        if (h[t]) atomicAdd(&btot[t], h[t]);
        return;
    }
    // ---- last block: stage bfrag ----
#pragma unroll
    for (int i = 0; i < 16; ++i) {
        int flat = i * 256 + t;          // 0..4095 = (nt*8+s)*64 + lane
        int lane = flat & 63;
        int idx = flat >> 6;
        int nt = idx >> 3, sfrag = idx & 7;
        int n = nt * 16 + (lane & 15);
        int kbase = sfrag * 32 + (lane >> 4) * 8;
        const float* srcp = (kbase < 128) ? (W + n * 128 + kbase)
                                          : (Bm + n * 128 + (kbase - 128));
        float4 v0 = *(const float4*)srcp;
        float4 v1 = *(const float4*)(srcp + 4);
        uint4 pk;
        pk.x = pack2(f_to_bf16(v0.x), f_to_bf16(v0.y));
        pk.y = pack2(f_to_bf16(v0.z), f_to_bf16(v0.w));
        pk.z = pack2(f_to_bf16(v1.x), f_to_bf16(v1.y));
        pk.w = pack2(f_to_bf16(v1.z), f_to_bf16(v1.w));
        bfrag[flat] = pk;
    }
}

// ---------------------------------------------------------------------------
// D2: bucket scatter. Each block self-derives the bucket bases from btot
// (1KB L2-hot read + LDS scan — replaces the serial scan256 dispatch), then:
// 1024 contiguous edges (coalesced reads), LDS per-bucket count -> ONE global
// atomicAdd per bucket into gcur0 (zeroed counters), then per-edge LDS rank ->
// write packed (local<<17 | dst) into the bucket region. Same-block writes
// fill whole lines -> ~no write amplification.
// ---------------------------------------------------------------------------
__global__ __launch_bounds__(256) void pass1_kernel(const int* __restrict__ ei,
                                                    const int* __restrict__ btot,
                                                    int* __restrict__ gcur0,
                                                    int* __restrict__ ebuf, int E) {
    __shared__ int sc[256];
    __shared__ int cnt[256];
    __shared__ int base[256];
    __shared__ int cur[256];
    int t = threadIdx.x;
    sc[t] = btot[t];
    cnt[t] = 0;
    cur[t] = 0;
    int e0 = blockIdx.x * 1024;
    __syncthreads();
    for (int d = 1; d < 256; d <<= 1) {
        int v = sc[t] + ((t >= d) ? sc[t - d] : 0);
        __syncthreads();
        sc[t] = v;
        __syncthreads();
    }
    int gbase_t = (t > 0) ? sc[t - 1] : 0;   // exclusive bucket start
    int s[4];
#pragma unroll
    for (int j = 0; j < 4; ++j) {
        int idx = e0 + j * 256 + t;
        s[j] = (idx < E) ? ei[idx] : -1;
        if (s[j] >= 0) atomicAdd(&cnt[s[j] >> 9], 1);
    }
    __syncthreads();
    int c = cnt[t];
    base[t] = c ? (gbase_t + atomicAdd(&gcur0[t], c)) : 0;
    __syncthreads();
#pragma unroll
    for (int j = 0; j < 4; ++j) {
        if (s[j] >= 0) {
            int idx = e0 + j * 256 + t;
            int bkt = s[j] >> 9;
            int r = atomicAdd(&cur[bkt], 1);
            int d = ei[E + idx];
            ebuf[base[bkt] + r] = ((s[j] & 511) << 17) | d;
        }
    }
}

// ---------------------------------------------------------------------------
// D3: per-bucket CSR finalize. Block g self-derives start/end from btot
// (LDS scan), then streams its contiguous ebuf region twice (L2-hot,
// coalesced): count per local node -> LDS scan(512) -> write off[] segment
// ENDS + place dsts contiguously into dst_sorted.
// ---------------------------------------------------------------------------
__global__ __launch_bounds__(256) void pass2_kernel(const int* __restrict__ ebuf,
                                                    const int* __restrict__ btot,
                                                    int* __restrict__ off,
                                                    int* __restrict__ dst_sorted,
                                                    int N, int NB) {
    __shared__ int gb[256];
    __shared__ int sc[512];
    __shared__ int cur[512];
    int g = blockIdx.x, t = threadIdx.x;
    int lo = g << 9;
    int hi = min(N, lo + 512);
    gb[t] = btot[t];
    sc[t] = 0;
    sc[t + 256] = 0;
    __syncthreads();
    for (int d = 1; d < 256; d <<= 1) {
        int v = gb[t] + ((t >= d) ? gb[t - d] : 0);
        __syncthreads();
        gb[t] = v;
        __syncthreads();
    }
    int start = (g > 0) ? gb[g - 1] : 0;
    int end = gb[g];
    for (int i = start + t; i < end; i += 256) atomicAdd(&sc[ebuf[i] >> 17], 1);
    __syncthreads();
    for (int d = 1; d < 512; d <<= 1) {
        int v0 = sc[t] + ((t >= d) ? sc[t - d] : 0);
        int i1 = t + 256;
        int v1 = sc[i1] + sc[i1 - d];
        __syncthreads();
        sc[t] = v0;
        sc[i1] = v1;
        __syncthreads();
    }
    if (lo + t < hi) off[lo + t] = start + sc[t];              // segment END
    cur[t] = (t == 0) ? 0 : sc[t - 1];
    {
        int i1 = t + 256;
        if (lo + i1 < hi) off[lo + i1] = start + sc[i1];
        cur[i1] = sc[i1 - 1];
    }
    __syncthreads();
    for (int i = start + t; i < end; i += 256) {
        int v = ebuf[i];
        int n = v >> 17;
        int r = atomicAdd(&cur[n], 1);
        dst_sorted[start + r] = v & 0x1FFFF;
    }
}

// ---------------------------------------------------------------------------
// D4: gather-aggregate (bf16 in/out, fp32 accumulate). 16 lanes/node,
// single predicated 8-wide batch per latency-round. XCD-AWARE BLOCK SWIZZLE:
// the 8 blocks covering gemm tile m get dispatch IDs == m (mod 8), so the agg
// rows each gemm tile reads were written on the SAME XCD's L2 (per-XCD L2s
// are not cross-coherent/shared; producer=consumer locality for the A-read).
// b -> r=b&7, q=b>>3, k=q>>3, s=q&7, tile m=r+8k, nodes [m*128+s*16, +16).
// Grid = 8*784 (bounds-checked; bijective onto all node chunks).
// ---------------------------------------------------------------------------
__global__ __launch_bounds__(256) void gather_bf16_kernel(const int* __restrict__ off,
                                                          const int* __restrict__ dst_sorted,
                                                          char* __restrict__ outb, int N) {
    int b = blockIdx.x;
    int r = b & 7, q = b >> 3;
    int k = q >> 3, s8 = q & 7;
    int m = r + 8 * k;
    int node = m * 128 + s8 * 16 + (threadIdx.x >> 4);
    int lane = threadIdx.x & 15;
    if (node >= N) return;
    int start = (node == 0) ? 0 : off[node - 1];
    int end = off[node];
    float acc[8];
#pragma unroll
    for (int i = 0; i < 8; ++i) acc[i] = 0.0f;

    const char* xb = outb;
    for (int j = start; j < end; j += 8) {
        uint4 v[8];
#pragma unroll
        for (int i = 0; i < 8; ++i) {
            int idx = j + i;
            int clamped = (idx < end) ? idx : (end - 1);
            int d = dst_sorted[clamped];
            v[i] = *(const uint4*)(xb + (size_t)d * 512 + 256 + lane * 16);
        }
#pragma unroll
        for (int i = 0; i < 8; ++i) {
            if (j + i >= end) v[i] = make_uint4(0u, 0u, 0u, 0u);  // mask (bf16 0 == +0.0f)
            acc[0] += bf16u_to_f_lo(v[i].x); acc[1] += bf16u_to_f_hi(v[i].x);
            acc[2] += bf16u_to_f_lo(v[i].y); acc[3] += bf16u_to_f_hi(v[i].y);
            acc[4] += bf16u_to_f_lo(v[i].z); acc[5] += bf16u_to_f_hi(v[i].z);
            acc[6] += bf16u_to_f_lo(v[i].w); acc[7] += bf16u_to_f_hi(v[i].w);
        }
    }
    int deg = end - start;
    float scale = (deg > 0) ? (1.0f / (float)deg) : 1.0f;
    unsigned short rr[8];
#pragma unroll
    for (int i = 0; i < 8; ++i) rr[i] = f_to_bf16(acc[i] * scale);
    uint4 pk;
    pk.x = pack2(rr[0], rr[1]);
    pk.y = pack2(rr[2], rr[3]);
    pk.z = pack2(rr[4], rr[5]);
    pk.w = pack2(rr[6], rr[7]);
    *(uint4*)(outb + (size_t)node * 512 + lane * 16) = pk;
}

// ---------------------------------------------------------------------------
// D5: MFMA GEMM (R7/R10-proven). One 128-row tile per block; A = bf16
// [agg|mirror] in out rows (K=256), M = [W;B] frags pre-staged in bfrag,
// async-copied 64KB to LDS; all 16 A-frag loads issued upfront (max MLP).
// Tile m runs on XCD m%8 — matching the gather swizzle, so the agg half of
// the A-read is local-L2-hot. In-place: each wave reads only its own rows.
// ---------------------------------------------------------------------------
__global__ __launch_bounds__(256, 2) void gemm_mfma_kernel(const uint4* __restrict__ bfrag,
                                                           float* __restrict__ out, int N) {
    __shared__ uint4 Bs[4096];  // 64 KB: Bs[(nt*8+s)*64 + lane]
    int t = threadIdx.x;
    int lane = t & 63;
    int w = t >> 6;
    int m16 = lane & 15;
    int quad = lane >> 4;

#pragma unroll
    for (int j = 0; j < 16; ++j)
        gload_lds16(bfrag + (w * 16 + j) * 64 + lane, &Bs[(w * 16 + j) * 64]);

    int rowbase = blockIdx.x * 128 + w * 32;
    short8 afrag[2][8];
#pragma unroll
    for (int g = 0; g < 2; ++g) {
        int arow = rowbase + g * 16 + m16;
        if (arow > N - 1) arow = N - 1;  // clamp; pollutes only discarded rows
        const char* ab = (const char*)out + (size_t)arow * 512;
#pragma unroll
        for (int s = 0; s < 8; ++s)
            afrag[g][s] = *(const short8*)(ab + s * 64 + quad * 16);
    }
    __syncthreads();   // drains global_load_lds (vmcnt) + barrier

    floatx4 acc[2][8];
#pragma unroll
    for (int g = 0; g < 2; ++g)
#pragma unroll
        for (int nt = 0; nt < 8; ++nt) acc[g][nt] = (floatx4){0.f, 0.f, 0.f, 0.f};

#pragma unroll
    for (int nt = 0; nt < 8; ++nt) {
#pragma unroll
        for (int s = 0; s < 8; ++s) {
            short8 bf = *(const short8*)&Bs[(nt * 8 + s) * 64 + lane];
            acc[0][nt] = __builtin_amdgcn_mfma_f32_16x16x32_bf16(afrag[0][s], bf, acc[0][nt], 0, 0, 0);
            acc[1][nt] = __builtin_amdgcn_mfma_f32_16x16x32_bf16(afrag[1][s], bf, acc[1][nt], 0, 0, 0);
        }
    }

#pragma unroll
    for (int g = 0; g < 2; ++g)
#pragma unroll
        for (int nt = 0; nt < 8; ++nt)
#pragma unroll
            for (int r = 0; r < 4; ++r) {
                int gr = rowbase + g * 16 + quad * 4 + r;
                if (gr < N) out[(size_t)gr * 128 + nt * 16 + m16] = acc[g][nt][r];
            }
}

// ---------------------------------------------------------------------------
// Atomic-scatter fallback (tiny ws / out-of-range N).
// ---------------------------------------------------------------------------
__global__ void zero_kernel(int* __restrict__ p, long n) {
    long i = (long)blockIdx.x * blockDim.x + threadIdx.x;
    long stride = (long)gridDim.x * blockDim.x;
    for (; i < n; i += stride) p[i] = 0;
}

__global__ void invdeg_kernel(int* __restrict__ deg_io, int N) {
    int i = blockIdx.x * blockDim.x + threadIdx.x;
    if (i < N) {
        int d = deg_io[i];
        float inv = (d > 0) ? (1.0f / (float)d) : 1.0f;
        ((float*)deg_io)[i] = inv;
    }
}

__global__ void hist_kernel(const int* __restrict__ src, int* __restrict__ cnt, int E) {
    int e = blockIdx.x * blockDim.x + threadIdx.x;
    if (e < E) atomicAdd(&cnt[src[e]], 1);
}

__global__ __launch_bounds__(128) void scatter_atomic_kernel(const float* __restrict__ x,
                                                             const int* __restrict__ ei,
                                                             const float* __restrict__ invdeg,
                                                             float* __restrict__ out, int E) {
    int e = blockIdx.x;
    int f = threadIdx.x;
    int s = ei[e];
    int d = ei[E + e];
    float v = x[(long)d * F_IN + f] * invdeg[s];
    atomicAdd(&out[(long)s * F_IN + f], v);
}

__global__ __launch_bounds__(256) void gemm_fused_kernel(const float* __restrict__ x,
                                                         const float* __restrict__ W,
                                                         const float* __restrict__ Bm,
                                                         float* __restrict__ out, int N) {
    __shared__ float As[64][68];
    __shared__ float Ms[64][132];
    int t = threadIdx.x;
    int row0 = blockIdx.x * 64;
    int c0 = (t & 31) * 4;
    int r0 = (t >> 5) * 8;
    float acc[8][4];
#pragma unroll
    for (int i = 0; i < 8; ++i)
#pragma unroll
        for (int j = 0; j < 4; ++j) acc[i][j] = 0.0f;

    for (int kc = 0; kc < 4; ++kc) {
        const float* Asrc = (kc < 2) ? out : x;
        const float* Msrc = (kc < 2) ? W : Bm;
        int k0 = (kc & 1) * 64;
#pragma unroll
        for (int i = 0; i < 4; ++i) {
            int flat = t + 256 * i;
            int m = flat >> 4, ks = flat & 15;
            int row = row0 + m;
            float4 v = make_float4(0.f, 0.f, 0.f, 0.f);
            if (row < N) v = *(const float4*)&Asrc[(long)row * 128 + k0 + ks * 4];
            As[ks * 4 + 0][m] = v.x;
            As[ks * 4 + 1][m] = v.y;
            As[ks * 4 + 2][m] = v.z;
            As[ks * 4 + 3][m] = v.w;
        }
#pragma unroll
        for (int i = 0; i < 8; ++i) {
            int flat = t + 256 * i;
            int c = flat >> 4, ks = flat & 15;
            float4 v = *(const float4*)&Msrc[(long)c * 128 + k0 + ks * 4];
            Ms[ks * 4 + 0][c] = v.x;
            Ms[ks * 4 + 1][c] = v.y;
            Ms[ks * 4 + 2][c] = v.z;
            Ms[ks * 4 + 3][c] = v.w;
        }
        __syncthreads();
#pragma unroll 8
        for (int kk = 0; kk < 64; ++kk) {
            float4 a0 = *(const float4*)&As[kk][r0];
            float4 a1 = *(const float4*)&As[kk][r0 + 4];
            float4 m0 = *(const float4*)&Ms[kk][c0];
            float a[8] = {a0.x, a0.y, a0.z, a0.w, a1.x, a1.y, a1.z, a1.w};
            float m[4] = {m0.x, m0.y, m0.z, m0.w};
#pragma unroll
            for (int i = 0; i < 8; ++i)
#pragma unroll
                for (int j = 0; j < 4; ++j) acc[i][j] += a[i] * m[j];
        }
        __syncthreads();
    }
#pragma unroll
    for (int i = 0; i < 8; ++i) {
        int row = row0 + r0 + i;
        if (row < N) {
            float4 v = make_float4(acc[i][0], acc[i][1], acc[i][2], acc[i][3]);
            *(float4*)&out[(long)row * 128 + c0] = v;
        }
    }
}

// ---------------------------------------------------------------------------

extern "C" void kernel_launch(void* const* d_in, const int* in_sizes, int n_in,
                              void* d_out, int out_size, void* d_ws, size_t ws_size,
                              hipStream_t stream) {
    const float* x = (const float*)d_in[0];
    const int* ei = (const int*)d_in[1];     // int32 per harness contract
    const float* W = (const float*)d_in[2];
    const float* Bm = (const float*)d_in[3];
    float* out = (float*)d_out;

    const int N = in_sizes[0] / F_IN;   // 100000
    const int E = in_sizes[1] / 2;      // 625000
    const int NB = (N + 511) >> 9;      // buckets of 512 nodes
    const int nbconv = (int)(((long)N * 32 + 255) / 256);
    const int nbhist = (E + 1023) / 1024;
    const int ntiles = (N + 127) / 128;

    // ws: bfrag[4096 u4] | btot[256] | gcur0[256] | off[N] | ebuf[E] | dst[E]
    const size_t need_main = 4096 * sizeof(uint4) +
                             ((size_t)512 + (size_t)N + 2 * (size_t)E) * sizeof(int);
    const size_t need_deg = (size_t)N * sizeof(int);

    if (ws_size >= need_main && N <= 131072) {
        uint4* bfrag = (uint4*)d_ws;            // 64KB, aligned
        int* btot    = (int*)(bfrag + 4096);
        int* gcur0   = btot + 256;
        int* off     = gcur0 + 256;
        int* ebuf    = off + N;
        int* dst_sorted = ebuf + E;

        hipMemsetAsync(btot, 0, 512 * sizeof(int), stream);  // btot + gcur0
        init_kernel<<<nbconv + nbhist + 1, 256, 0, stream>>>(x, (char*)out, W, Bm,
                                                             bfrag, btot, ei, N, E,
                                                             nbconv, nbhist);
        pass1_kernel<<<(E + 1023) / 1024, 256, 0, stream>>>(ei, btot, gcur0, ebuf, E);
        pass2_kernel<<<NB, 256, 0, stream>>>(ebuf, btot, off, dst_sorted, N, NB);
        {
            // XCD-swizzled gather grid: 8 * (ceil(ntiles/8) * 8) blocks
            int kmax = (ntiles + 7) / 8;         // tiles per XCD residue class
            int grid = 8 * kmax * 8;             // r x k x s
            gather_bf16_kernel<<<grid, 256, 0, stream>>>(off, dst_sorted, (char*)out, N);
        }
        gemm_mfma_kernel<<<ntiles, 256, 0, stream>>>(bfrag, out, N);
    } else if (ws_size >= need_deg) {
        // -------- atomic scatter fallback --------
        int* deg = (int*)d_ws;
        zero_kernel<<<256, 256, 0, stream>>>(deg, N);
        hist_kernel<<<(E + 255) / 256, 256, 0, stream>>>(ei, deg, E);
        invdeg_kernel<<<(N + 255) / 256, 256, 0, stream>>>(deg, N);
        zero_kernel<<<512, 256, 0, stream>>>((int*)out, (long)N * F_IN);
        scatter_atomic_kernel<<<E, 128, 0, stream>>>(x, ei, (const float*)deg, out, E);
        gemm_fused_kernel<<<(N + 63) / 64, 256, 0, stream>>>(x, W, Bm, out, N);
    }
}